// Round 10
// baseline (288.544 us; speedup 1.0000x reference)
//
#include <hip/hip_runtime.h>
#include <hip/hip_bf16.h>

// GroupSupConLoss: loss = mean_i[ lse_i - mean_pos_i ] over anchors with positives.
// sim = E E^T / tau, B=8192, D=1024, tau=0.1.
// R8: maximize blocks/CU, minimize bytes/block-iter. Evidence R4-R7: staging
// throughput is ~10 GB/s PER BLOCK regardless of vmcnt depth/tile size (per-
// block LDS-fill queue wall). So: BK=32, 2-buffer LDS = 32 KiB, launch_bounds
// (256,4) => VGPR<=128 => 4 blocks/CU (was 2). 2-phase R5 ordering (race-free),
// R7's conflict-free BK=32 swizzle. Diagonal tiles skip B staging (B==A).

#define NROWS 8192
#define DIM   1024
#define TAU_INV 10.0f

#define BM 128
#define BN 128
#define BK 32
#define NTILE (NROWS / BM)                 // 64
#define NBLOCKS (NTILE * (NTILE + 1) / 2)  // 2080
#define NKT (DIM / BK)                     // 32
#define ABUF_SHORTS (BM * BK)              // 4096 shorts = 8 KiB
#define BUF_SHORTS (2 * ABUF_SHORTS)       // A+B = 16 KiB

typedef __attribute__((ext_vector_type(8))) short short8;
typedef __attribute__((ext_vector_type(4))) float f32x4;

__global__ void convert_bf16_kernel(const float* __restrict__ in,
                                    unsigned short* __restrict__ out,
                                    float* __restrict__ accum_zero, int n4) {
    int gid = blockIdx.x * blockDim.x + threadIdx.x;
    if (gid < 3 * NROWS / 4) {
        float4 z; z.x = 0.f; z.y = 0.f; z.z = 0.f; z.w = 0.f;
        ((float4*)accum_zero)[gid] = z;
    }
    const int stride = gridDim.x * blockDim.x;
    for (int i = gid; i < n4; i += stride) {
        float4 v = ((const float4*)in)[i];
        __hip_bfloat16 b0 = __float2bfloat16(v.x);
        __hip_bfloat16 b1 = __float2bfloat16(v.y);
        __hip_bfloat16 b2 = __float2bfloat16(v.z);
        __hip_bfloat16 b3 = __float2bfloat16(v.w);
        ushort4 o;
        o.x = *(unsigned short*)&b0;
        o.y = *(unsigned short*)&b1;
        o.z = *(unsigned short*)&b2;
        o.w = *(unsigned short*)&b3;
        ((ushort4*)out)[i] = o;
    }
}

__device__ __forceinline__ void gload_lds16(const short* g, short* l) {
    __builtin_amdgcn_global_load_lds(
        (const __attribute__((address_space(1))) unsigned*)g,
        (__attribute__((address_space(3))) unsigned*)l, 16, 0, 0);
}

__launch_bounds__(256, 4)
__global__ void simloss_kernel(const unsigned short* __restrict__ ebf_u,
                               const int* __restrict__ labels,
                               float* __restrict__ exp_sum,
                               float* __restrict__ pos_sum,
                               float* __restrict__ pos_cnt) {
    // 2 buffers x (A 8KiB + B 8KiB) = 32 KiB -> 4 blocks/CU (with VGPR<=128)
    __shared__ short lds[2 * BUF_SHORTS];

    const int tid  = threadIdx.x;
    const int lane = tid & 63;
    const int wid  = tid >> 6;   // 0..3
    const int wrow = wid >> 1;   // 0..1
    const int wcol = wid & 1;    // 0..1

    // XCD-aware bijective swizzle: 2080 % 8 == 0.
    const int tile = (blockIdx.x & 7) * (NBLOCKS / 8) + (blockIdx.x >> 3);

    // decode tile -> upper-triangular (ti, tj), ti <= tj
    int u = tile, ti = 0, rowlen = NTILE;
    while (u >= rowlen) { u -= rowlen; ++ti; --rowlen; }
    const int tj = ti + u;
    const int i0 = ti * BM;
    const int j0 = tj * BN;
    const bool offdiag = (ti != tj);

    const short* eg = (const short*)ebf_u;

    f32x4 acc[4][4];
#pragma unroll
    for (int m = 0; m < 4; ++m)
#pragma unroll
        for (int n = 0; n < 4; ++n)
            acc[m][n] = (f32x4)0.0f;

    // Staging: 1 KiB chunk = 16 rows x 32 bf16. lane l -> row l>>2, LDS 16B
    // slot l&3. Read swizzle: slot = g ^ ((row>>1)&3); staging pre-swizzles
    // the GLOBAL column-group so LDS dst stays linear. R7-verified: 0 conflicts.
    const int lrow = lane >> 2;                       // 0..15 row in chunk
    const int csrc = (lane & 3) ^ ((lane >> 3) & 3);  // swizzled global col-group

    // Diagonal tiles: B panel == A panel; skip B staging, read B from A buffer.
#define STAGE(t, b)                                                          \
    {                                                                        \
        short* Ab = lds + (b) * BUF_SHORTS;                                  \
        const int kc = (t) * BK + csrc * 8;                                  \
        _Pragma("unroll")                                                    \
        for (int c = 0; c < 2; ++c) {                                        \
            const int ch = wid * 2 + c;            /* chunk 0..7 */          \
            const int gr = ch * 16 + lrow;         /* row 0..127 */          \
            gload_lds16(eg + (size_t)(i0 + gr) * DIM + kc, Ab + ch * 512);   \
            if (offdiag)                                                     \
                gload_lds16(eg + (size_t)(j0 + gr) * DIM + kc,               \
                            Ab + ABUF_SHORTS + ch * 512);                    \
        }                                                                    \
    }

    // ---- prologue: stage K-tile 0 into buffer 0 ----
    STAGE(0, 0)
    __syncthreads();   // drains vmcnt: buffer 0 ready

    const int g = lane >> 4;          // K col-group 0..3 (8 elems each)
    const int boff = offdiag ? ABUF_SHORTS : 0;

#pragma unroll 1
    for (int t = 0; t < NKT; ++t) {
        const int cur = t & 1;
        // prefetch next K-tile into the other buffer (safe: other buffer's
        // readers all passed the barrier that ended iter t-1)
        if (t + 1 < NKT) STAGE(t + 1, cur ^ 1)

        const short* Ab = lds + cur * BUF_SHORTS;
        const short* Bb = Ab + boff;

        short8 af[4], bf[4];
#pragma unroll
        for (int m = 0; m < 4; ++m) {
            const int r = wrow * 64 + m * 16 + (lane & 15);
            af[m] = *(const short8*)(Ab + r * BK + ((g ^ ((r >> 1) & 3)) << 3));
        }
#pragma unroll
        for (int n = 0; n < 4; ++n) {
            const int r = wcol * 64 + n * 16 + (lane & 15);
            bf[n] = *(const short8*)(Bb + r * BK + ((g ^ ((r >> 1) & 3)) << 3));
        }
        __builtin_amdgcn_s_setprio(1);
#pragma unroll
        for (int m = 0; m < 4; ++m)
#pragma unroll
            for (int n = 0; n < 4; ++n)
                acc[m][n] = __builtin_amdgcn_mfma_f32_16x16x32_bf16(
                    af[m], bf[n], acc[m][n], 0, 0, 0);
        __builtin_amdgcn_s_setprio(0);

        __syncthreads();   // next buffer ready; current safe to overwrite
    }
#undef STAGE

    // ---- fused epilogue ----
    // C/D layout: col = lane&15, row = (lane>>4)*4 + reg
    const int rowbase = i0 + wrow * 64;
    const int colbase = j0 + wcol * 64;

    int lc[4];
#pragma unroll
    for (int n = 0; n < 4; ++n)
        lc[n] = labels[colbase + n * 16 + (lane & 15)];

    float ecol[4] = {0, 0, 0, 0};
    float pcol[4] = {0, 0, 0, 0};
    float ccol[4] = {0, 0, 0, 0};

#pragma unroll
    for (int m = 0; m < 4; ++m) {
#pragma unroll
        for (int r = 0; r < 4; ++r) {
            const int row = rowbase + m * 16 + (lane >> 4) * 4 + r;
            const int lr = labels[row];
            float e = 0.0f, p = 0.0f, c = 0.0f;
#pragma unroll
            for (int n = 0; n < 4; ++n) {
                const int col = colbase + n * 16 + (lane & 15);
                const float s = acc[m][n][r] * TAU_INV;
                const bool diag = (row == col);
                const float ex = diag ? 0.0f : __expf(s);
                const bool same = (lr == lc[n]) && !diag;
                const float ps = same ? s : 0.0f;
                const float cs = same ? 1.0f : 0.0f;
                e += ex; p += ps; c += cs;
                ecol[n] += ex; pcol[n] += ps; ccol[n] += cs;
            }
#pragma unroll
            for (int off = 1; off < 16; off <<= 1) {
                e += __shfl_xor(e, off);
                p += __shfl_xor(p, off);
                c += __shfl_xor(c, off);
            }
            if ((lane & 15) == 0) {
                atomicAdd(&exp_sum[row], e);
                atomicAdd(&pos_sum[row], p);
                atomicAdd(&pos_cnt[row], c);
            }
        }
    }

    // col-side (mirror) contributions for off-diagonal tiles.
    if (offdiag) {
#pragma unroll
        for (int n = 0; n < 4; ++n) {
#pragma unroll
            for (int off = 16; off < 64; off <<= 1) {
                ecol[n] += __shfl_xor(ecol[n], off);
                pcol[n] += __shfl_xor(pcol[n], off);
                ccol[n] += __shfl_xor(ccol[n], off);
            }
            if (lane < 16) {
                const int row = colbase + n * 16 + lane;
                atomicAdd(&exp_sum[row], ecol[n]);
                atomicAdd(&pos_sum[row], pcol[n]);
                atomicAdd(&pos_cnt[row], ccol[n]);
            }
        }
    }
}

__global__ void finalize_kernel(const float* __restrict__ exp_sum,
                                const float* __restrict__ pos_sum,
                                const float* __restrict__ pos_cnt,
                                float* __restrict__ out) {
    __shared__ float s_l[8];
    __shared__ float s_c[8];
    float lsum = 0.0f, csum = 0.0f;
    for (int i4 = threadIdx.x; i4 < NROWS / 4; i4 += blockDim.x) {
        float4 e4 = ((const float4*)exp_sum)[i4];
        float4 p4 = ((const float4*)pos_sum)[i4];
        float4 c4 = ((const float4*)pos_cnt)[i4];
        const float es[4] = {e4.x, e4.y, e4.z, e4.w};
        const float ps[4] = {p4.x, p4.y, p4.z, p4.w};
        const float cs[4] = {c4.x, c4.y, c4.z, c4.w};
#pragma unroll
        for (int k = 0; k < 4; ++k) {
            const bool has = cs[k] > 0.5f;
            const float li = logf(es[k]) - ps[k] / fmaxf(cs[k], 1.0f);
            lsum += has ? li : 0.0f;
            csum += has ? 1.0f : 0.0f;
        }
    }
#pragma unroll
    for (int off = 1; off < 64; off <<= 1) {
        lsum += __shfl_xor(lsum, off);
        csum += __shfl_xor(csum, off);
    }
    const int w = threadIdx.x >> 6;
    if ((threadIdx.x & 63) == 0) { s_l[w] = lsum; s_c[w] = csum; }
    __syncthreads();
    if (threadIdx.x == 0) {
        float L = 0.0f, C = 0.0f;
        for (int i = 0; i < (int)(blockDim.x >> 6); ++i) { L += s_l[i]; C += s_c[i]; }
        out[0] = L / fmaxf(C, 1.0f);
    }
}

extern "C" void kernel_launch(void* const* d_in, const int* in_sizes, int n_in,
                              void* d_out, int out_size, void* d_ws, size_t ws_size,
                              hipStream_t stream) {
    const float* emb   = (const float*)d_in[0];
    const int* labels  = (const int*)d_in[1];
    float* out         = (float*)d_out;

    char* ws = (char*)d_ws;
    unsigned short* ebf = (unsigned short*)ws;                       // 16 MiB
    float* exp_sum = (float*)(ws + (size_t)NROWS * DIM * 2);         // 3*32 KiB
    float* pos_sum = exp_sum + NROWS;
    float* pos_cnt = exp_sum + 2 * NROWS;

    convert_bf16_kernel<<<1024, 256, 0, stream>>>(emb, ebf, exp_sum, NROWS * DIM / 4);
    simloss_kernel<<<NBLOCKS, 256, 0, stream>>>(ebf, labels, exp_sum, pos_sum, pos_cnt);
    finalize_kernel<<<1, 256, 0, stream>>>(exp_sum, pos_sum, pos_cnt, out);
}

// Round 11
// 228.870 us; speedup vs baseline: 1.2607x; 1.2607x over previous
//
#include <hip/hip_runtime.h>
#include <hip/hip_bf16.h>

// GroupSupConLoss: loss = mean_i[ lse_i - mean_pos_i ] over anchors with positives.
// sim = E E^T / tau, B=8192, D=1024, tau=0.1.
// R9: (a) fix R8's spill: launch_bounds(256,3) -> ~170 regs/wave (64 AGPR acc
// + ~106 arch), 3 blocks/CU; R8's (256,4) forced VGPR=64 and spilled 175 MB
// to scratch (WRITE 31->206 MB). (b) supertile (8x8 tiles) ordering: one
// supertile's 8 A-panels + 8 B-panels = 4 MB = one XCD L2, serving 64 tiles
// (was: row streaming 16 MB of B-panels per tile-row -> 267 MB L2-miss fetch).

#define NROWS 8192
#define DIM   1024
#define TAU_INV 10.0f

#define BM 128
#define BN 128
#define BK 32
#define NTILE (NROWS / BM)                 // 64
#define NBLOCKS (NTILE * (NTILE + 1) / 2)  // 2080
#define NKT (DIM / BK)                     // 32
#define ABUF_SHORTS (BM * BK)              // 4096 shorts = 8 KiB
#define BUF_SHORTS (2 * ABUF_SHORTS)       // A+B = 16 KiB

typedef __attribute__((ext_vector_type(8))) short short8;
typedef __attribute__((ext_vector_type(4))) float f32x4;

__global__ void convert_bf16_kernel(const float* __restrict__ in,
                                    unsigned short* __restrict__ out,
                                    float* __restrict__ accum_zero, int n4) {
    int gid = blockIdx.x * blockDim.x + threadIdx.x;
    if (gid < 3 * NROWS / 4) {
        float4 z; z.x = 0.f; z.y = 0.f; z.z = 0.f; z.w = 0.f;
        ((float4*)accum_zero)[gid] = z;
    }
    const int stride = gridDim.x * blockDim.x;
    for (int i = gid; i < n4; i += stride) {
        float4 v = ((const float4*)in)[i];
        __hip_bfloat16 b0 = __float2bfloat16(v.x);
        __hip_bfloat16 b1 = __float2bfloat16(v.y);
        __hip_bfloat16 b2 = __float2bfloat16(v.z);
        __hip_bfloat16 b3 = __float2bfloat16(v.w);
        ushort4 o;
        o.x = *(unsigned short*)&b0;
        o.y = *(unsigned short*)&b1;
        o.z = *(unsigned short*)&b2;
        o.w = *(unsigned short*)&b3;
        ((ushort4*)out)[i] = o;
    }
}

__device__ __forceinline__ void gload_lds16(const short* g, short* l) {
    __builtin_amdgcn_global_load_lds(
        (const __attribute__((address_space(1))) unsigned*)g,
        (__attribute__((address_space(3))) unsigned*)l, 16, 0, 0);
}

__launch_bounds__(256, 3)
__global__ void simloss_kernel(const unsigned short* __restrict__ ebf_u,
                               const int* __restrict__ labels,
                               float* __restrict__ exp_sum,
                               float* __restrict__ pos_sum,
                               float* __restrict__ pos_cnt) {
    // 2 buffers x (A 8KiB + B 8KiB) = 32 KiB
    __shared__ short lds[2 * BUF_SHORTS];

    const int tid  = threadIdx.x;
    const int lane = tid & 63;
    const int wid  = tid >> 6;   // 0..3
    const int wrow = wid >> 1;   // 0..1
    const int wcol = wid & 1;    // 0..1

    // XCD-aware bijective swizzle: 2080 % 8 == 0, 260-tile contiguous band/XCD.
    const int tile = (blockIdx.x & 7) * (NBLOCKS / 8) + (blockIdx.x >> 3);

    // ---- supertile decode: 8x8-tile supertiles, upper-tri; within a
    // supertile row-major. One supertile's panels = 4 MB = one XCD L2. ----
    int L = tile;
    int sti = 0, stj = 0;
    {
        bool found = false;
        for (int si = 0; si < 8 && !found; ++si) {
            for (int sj = si; sj < 8; ++sj) {
                const int cnt = (si == sj) ? 36 : 64;
                if (L < cnt) { sti = si; stj = sj; found = true; break; }
                L -= cnt;
            }
        }
    }
    int ta, tb;
    if (sti == stj) {            // diagonal supertile: upper-tri 8x8
        int r = 0, len = 8;
        while (L >= len) { L -= len; ++r; --len; }
        ta = r; tb = r + L;
    } else {                     // full 8x8
        ta = L >> 3; tb = L & 7;
    }
    const int ti = sti * 8 + ta;
    const int tj = stj * 8 + tb;
    const int i0 = ti * BM;
    const int j0 = tj * BN;
    const bool offdiag = (ti != tj);

    const short* eg = (const short*)ebf_u;

    f32x4 acc[4][4];
#pragma unroll
    for (int m = 0; m < 4; ++m)
#pragma unroll
        for (int n = 0; n < 4; ++n)
            acc[m][n] = (f32x4)0.0f;

    // Staging: 1 KiB chunk = 16 rows x 32 bf16. lane l -> row l>>2, LDS 16B
    // slot l&3. Read swizzle: slot = g ^ ((row>>1)&3); staging pre-swizzles
    // the GLOBAL column-group so LDS dst stays linear. R7-verified: 0 conflicts.
    const int lrow = lane >> 2;                       // 0..15 row in chunk
    const int csrc = (lane & 3) ^ ((lane >> 3) & 3);  // swizzled global col-group

    // Diagonal tiles: B panel == A panel; skip B staging, read B from A buffer.
#define STAGE(t, b)                                                          \
    {                                                                        \
        short* Ab = lds + (b) * BUF_SHORTS;                                  \
        const int kc = (t) * BK + csrc * 8;                                  \
        _Pragma("unroll")                                                    \
        for (int c = 0; c < 2; ++c) {                                        \
            const int ch = wid * 2 + c;            /* chunk 0..7 */          \
            const int gr = ch * 16 + lrow;         /* row 0..127 */          \
            gload_lds16(eg + (size_t)(i0 + gr) * DIM + kc, Ab + ch * 512);   \
            if (offdiag)                                                     \
                gload_lds16(eg + (size_t)(j0 + gr) * DIM + kc,               \
                            Ab + ABUF_SHORTS + ch * 512);                    \
        }                                                                    \
    }

    // ---- prologue: stage K-tile 0 into buffer 0 ----
    STAGE(0, 0)
    __syncthreads();   // drains vmcnt: buffer 0 ready

    const int g = lane >> 4;          // K col-group 0..3 (8 elems each)
    const int boff = offdiag ? ABUF_SHORTS : 0;

#pragma unroll 1
    for (int t = 0; t < NKT; ++t) {
        const int cur = t & 1;
        // prefetch next K-tile into the other buffer (safe: other buffer's
        // readers all passed the barrier that ended iter t-1)
        if (t + 1 < NKT) STAGE(t + 1, cur ^ 1)

        const short* Ab = lds + cur * BUF_SHORTS;
        const short* Bb = Ab + boff;

        short8 af[4], bf[4];
#pragma unroll
        for (int m = 0; m < 4; ++m) {
            const int r = wrow * 64 + m * 16 + (lane & 15);
            af[m] = *(const short8*)(Ab + r * BK + ((g ^ ((r >> 1) & 3)) << 3));
        }
#pragma unroll
        for (int n = 0; n < 4; ++n) {
            const int r = wcol * 64 + n * 16 + (lane & 15);
            bf[n] = *(const short8*)(Bb + r * BK + ((g ^ ((r >> 1) & 3)) << 3));
        }
        __builtin_amdgcn_s_setprio(1);
#pragma unroll
        for (int m = 0; m < 4; ++m)
#pragma unroll
            for (int n = 0; n < 4; ++n)
                acc[m][n] = __builtin_amdgcn_mfma_f32_16x16x32_bf16(
                    af[m], bf[n], acc[m][n], 0, 0, 0);
        __builtin_amdgcn_s_setprio(0);

        __syncthreads();   // next buffer ready; current safe to overwrite
    }
#undef STAGE

    // ---- fused epilogue ----
    // C/D layout: col = lane&15, row = (lane>>4)*4 + reg
    const int rowbase = i0 + wrow * 64;
    const int colbase = j0 + wcol * 64;

    int lc[4];
#pragma unroll
    for (int n = 0; n < 4; ++n)
        lc[n] = labels[colbase + n * 16 + (lane & 15)];

    float ecol[4] = {0, 0, 0, 0};
    float pcol[4] = {0, 0, 0, 0};
    float ccol[4] = {0, 0, 0, 0};

#pragma unroll
    for (int m = 0; m < 4; ++m) {
#pragma unroll
        for (int r = 0; r < 4; ++r) {
            const int row = rowbase + m * 16 + (lane >> 4) * 4 + r;
            const int lr = labels[row];
            float e = 0.0f, p = 0.0f, c = 0.0f;
#pragma unroll
            for (int n = 0; n < 4; ++n) {
                const int col = colbase + n * 16 + (lane & 15);
                const float s = acc[m][n][r] * TAU_INV;
                const bool diag = (row == col);
                const float ex = diag ? 0.0f : __expf(s);
                const bool same = (lr == lc[n]) && !diag;
                const float ps = same ? s : 0.0f;
                const float cs = same ? 1.0f : 0.0f;
                e += ex; p += ps; c += cs;
                ecol[n] += ex; pcol[n] += ps; ccol[n] += cs;
            }
#pragma unroll
            for (int off = 1; off < 16; off <<= 1) {
                e += __shfl_xor(e, off);
                p += __shfl_xor(p, off);
                c += __shfl_xor(c, off);
            }
            if ((lane & 15) == 0) {
                atomicAdd(&exp_sum[row], e);
                atomicAdd(&pos_sum[row], p);
                atomicAdd(&pos_cnt[row], c);
            }
        }
    }

    // col-side (mirror) contributions for off-diagonal tiles.
    if (offdiag) {
#pragma unroll
        for (int n = 0; n < 4; ++n) {
#pragma unroll
            for (int off = 16; off < 64; off <<= 1) {
                ecol[n] += __shfl_xor(ecol[n], off);
                pcol[n] += __shfl_xor(pcol[n], off);
                ccol[n] += __shfl_xor(ccol[n], off);
            }
            if (lane < 16) {
                const int row = colbase + n * 16 + lane;
                atomicAdd(&exp_sum[row], ecol[n]);
                atomicAdd(&pos_sum[row], pcol[n]);
                atomicAdd(&pos_cnt[row], ccol[n]);
            }
        }
    }
}

__global__ void finalize_kernel(const float* __restrict__ exp_sum,
                                const float* __restrict__ pos_sum,
                                const float* __restrict__ pos_cnt,
                                float* __restrict__ out) {
    __shared__ float s_l[8];
    __shared__ float s_c[8];
    float lsum = 0.0f, csum = 0.0f;
    for (int i4 = threadIdx.x; i4 < NROWS / 4; i4 += blockDim.x) {
        float4 e4 = ((const float4*)exp_sum)[i4];
        float4 p4 = ((const float4*)pos_sum)[i4];
        float4 c4 = ((const float4*)pos_cnt)[i4];
        const float es[4] = {e4.x, e4.y, e4.z, e4.w};
        const float ps[4] = {p4.x, p4.y, p4.z, p4.w};
        const float cs[4] = {c4.x, c4.y, c4.z, c4.w};
#pragma unroll
        for (int k = 0; k < 4; ++k) {
            const bool has = cs[k] > 0.5f;
            const float li = logf(es[k]) - ps[k] / fmaxf(cs[k], 1.0f);
            lsum += has ? li : 0.0f;
            csum += has ? 1.0f : 0.0f;
        }
    }
#pragma unroll
    for (int off = 1; off < 64; off <<= 1) {
        lsum += __shfl_xor(lsum, off);
        csum += __shfl_xor(csum, off);
    }
    const int w = threadIdx.x >> 6;
    if ((threadIdx.x & 63) == 0) { s_l[w] = lsum; s_c[w] = csum; }
    __syncthreads();
    if (threadIdx.x == 0) {
        float L = 0.0f, C = 0.0f;
        for (int i = 0; i < (int)(blockDim.x >> 6); ++i) { L += s_l[i]; C += s_c[i]; }
        out[0] = L / fmaxf(C, 1.0f);
    }
}

extern "C" void kernel_launch(void* const* d_in, const int* in_sizes, int n_in,
                              void* d_out, int out_size, void* d_ws, size_t ws_size,
                              hipStream_t stream) {
    const float* emb   = (const float*)d_in[0];
    const int* labels  = (const int*)d_in[1];
    float* out         = (float*)d_out;

    char* ws = (char*)d_ws;
    unsigned short* ebf = (unsigned short*)ws;                       // 16 MiB
    float* exp_sum = (float*)(ws + (size_t)NROWS * DIM * 2);         // 3*32 KiB
    float* pos_sum = exp_sum + NROWS;
    float* pos_cnt = exp_sum + 2 * NROWS;

    convert_bf16_kernel<<<1024, 256, 0, stream>>>(emb, ebf, exp_sum, NROWS * DIM / 4);
    simloss_kernel<<<NBLOCKS, 256, 0, stream>>>(ebf, labels, exp_sum, pos_sum, pos_cnt);
    finalize_kernel<<<1, 256, 0, stream>>>(exp_sum, pos_sum, pos_cnt, out);
}